// Round 17
// baseline (338.409 us; speedup 1.0000x reference)
//
#include <hip/hip_runtime.h>
#include <hip/hip_bf16.h>

#define NROW 10000
#define NF 256
#define KF 512
#define MP 10048   // padded row/K extent (157*64)
#define NKT 157    // K-tiles of 64
#define NT32 313   // M-tiles of 32 (313*32 = 10016)

typedef __attribute__((ext_vector_type(8))) short short8x;
typedef __attribute__((ext_vector_type(4))) float f32x4;

// native RNE convert + pack (gfx950 hardware cvt; compiler fuses pairs)
__device__ __forceinline__ unsigned int pkbf16(float a, float b){
  union { __hip_bfloat16 h[2]; unsigned int u; } cv;
  cv.h[0] = __float2bfloat16(a);
  cv.h[1] = __float2bfloat16(b);
  return cv.u;
}

// ---------------- k_prep3: fused degree + bf16 convert (NATIVE cvt).
// One wave per FULL row. 5 iterations of {8 nontemporal loads -> patch
// diag/sum -> 4 uint4 stores}.
//   adjb[r][k] = bf16(Ahat[r][k])  (diag=1, cols>=10000 zeroed)
//   degp[r]    = patched row sum (== degree)
__global__ __launch_bounds__(256) void k_prep3(const float* __restrict__ adj,
        unsigned short* __restrict__ adjb, float* __restrict__ degp){
  int t = threadIdx.x, lane = t & 63;
  int row = blockIdx.x * 4 + (t >> 6);          // 2500*4 = 10000 exact
  const f32x4* src = (const f32x4*)(adj + (size_t)row * NROW);  // 2500 slots
  unsigned short* dst = adjb + (size_t)row * MP;                // 2512 slots
  const f32x4 zero4 = {0.f, 0.f, 0.f, 0.f};
  f32x4 sacc = zero4;

  for (int it = 0; it < 5; ++it){
    int base = it * 512 + lane * 2;             // even f32x4 slot
    f32x4 v[8];
    #pragma unroll
    for (int s = 0; s < 4; ++s){
      int fi = base + s * 128;
      v[2*s]   = (fi     < 2500) ? __builtin_nontemporal_load(src + fi)     : zero4;
      v[2*s+1] = (fi + 1 < 2500) ? __builtin_nontemporal_load(src + fi + 1) : zero4;
    }
    #pragma unroll
    for (int s = 0; s < 4; ++s){
      int fi = base + s * 128;
      int gc0 = fi * 4, gc1 = gc0 + 4;
      f32x4 w0 = v[2*s], w1 = v[2*s+1];
      if (row == gc0    ) w0[0] = 1.f;
      if (row == gc0 + 1) w0[1] = 1.f;
      if (row == gc0 + 2) w0[2] = 1.f;
      if (row == gc0 + 3) w0[3] = 1.f;
      if (row == gc1    ) w1[0] = 1.f;
      if (row == gc1 + 1) w1[1] = 1.f;
      if (row == gc1 + 2) w1[2] = 1.f;
      if (row == gc1 + 3) w1[3] = 1.f;
      sacc += w0; sacc += w1;
      uint4 o;
      o.x = pkbf16(w0[0], w0[1]);
      o.y = pkbf16(w0[2], w0[3]);
      o.z = pkbf16(w1[0], w1[1]);
      o.w = pkbf16(w1[2], w1[3]);
      if (fi < 2512) *(uint4*)(dst + gc0) = o;  // covers K-pad zeros too
    }
  }
  float s = (sacc[0] + sacc[1]) + (sacc[2] + sacc[3]);
  #pragma unroll
  for (int off = 32; off; off >>= 1) s += __shfl_down(s, off);
  if (lane == 0) degp[row] = s;
}

// ---------------- k_dinv: dinv[i] = rsqrt(deg); zero hsT K-tail rows
__global__ void k_dinv(const float* __restrict__ degp, float* __restrict__ dinv,
                       unsigned short* __restrict__ hsT){
  int i = blockIdx.x * 256 + threadIdx.x;
  if (i >= MP) return;
  float d = 0.f;
  if (i < NROW){
    float tot = degp[i];                        // already diag-patched
    d = tot > 0.f ? rsqrtf(tot) : 0.f;
  }
  dinv[i] = d;
  if (i < NF){                 // zero hsT[i][10000..10048)
    unsigned int* tz = (unsigned int*)(hsT + (size_t)i * MP + NROW);
    #pragma unroll
    for (int m = 0; m < (MP - NROW) / 2; ++m) tz[m] = 0u;
  }
}

// ---------------- k_featw: hsT[c][i] = bf16(dinv[i]*(feat@W)[i][c])
__global__ __launch_bounds__(128) void k_featw(const float* __restrict__ feat,
        const float* __restrict__ W, const float* __restrict__ dinv,
        unsigned short* __restrict__ hsT){
  __shared__ __align__(16) float fs[8][512];   // 16 KB
  int t = threadIdx.x;        // 0..127
  int i0 = blockIdx.x * 8;    // 1250*8 = 10000 exact
  #pragma unroll
  for (int it = 0; it < 8; ++it){
    int idx = it * 128 + t;
    int r = idx >> 7, c4 = (idx & 127) * 4;
    *(float4*)&fs[r][c4] = *(const float4*)(feat + (size_t)(i0 + r) * KF + c4);
  }
  __syncthreads();
  float acc[8][2];
  #pragma unroll
  for (int r = 0; r < 8; ++r){ acc[r][0] = 0.f; acc[r][1] = 0.f; }
  int c0 = t, c1 = t + 128;
  for (int k = 0; k < KF; k += 4){
    const float* Wk = W + (size_t)k * NF;
    float w0a = Wk[c0],        w0b = Wk[c1];
    float w1a = Wk[NF + c0],   w1b = Wk[NF + c1];
    float w2a = Wk[2*NF + c0], w2b = Wk[2*NF + c1];
    float w3a = Wk[3*NF + c0], w3b = Wk[3*NF + c1];
    #pragma unroll
    for (int r = 0; r < 8; ++r){
      float4 f = *(const float4*)&fs[r][k];
      float a0 = acc[r][0], a1 = acc[r][1];
      a0 = fmaf(f.x, w0a, a0); a1 = fmaf(f.x, w0b, a1);
      a0 = fmaf(f.y, w1a, a0); a1 = fmaf(f.y, w1b, a1);
      a0 = fmaf(f.z, w2a, a0); a1 = fmaf(f.z, w2b, a1);
      a0 = fmaf(f.w, w3a, a0); a1 = fmaf(f.w, w3b, a1);
      acc[r][0] = a0; acc[r][1] = a1;
    }
  }
  float dv[8];
  #pragma unroll
  for (int r = 0; r < 8; ++r) dv[r] = dinv[i0 + r];
  unsigned short* d0 = hsT + (size_t)c0 * MP + i0;
  unsigned short* d1 = hsT + (size_t)c1 * MP + i0;
  #pragma unroll
  for (int r = 0; r < 8; r += 2){
    unsigned int u0 = pkbf16(acc[r][0] * dv[r], acc[r+1][0] * dv[r+1]);
    unsigned int u1 = pkbf16(acc[r][1] * dv[r], acc[r+1][1] * dv[r+1]);
    *(unsigned int*)(d0 + r) = u0;
    *(unsigned int*)(d1 + r) = u1;
  }
}

// ---------------- k_gemm: KSPLIT=1 (R16 analysis: atomics were ~300MB of
// HBM write-through -- the gemm was BW-bound on waste). BM=32, grid 313,
// full K per block, plain stores, epilogue fused (dinv scale + bias + relu).
__global__ __launch_bounds__(256, 3) void k_gemm(const unsigned short* __restrict__ adjb,
        const unsigned short* __restrict__ hsT, const float* __restrict__ dinv,
        const float* __restrict__ cb, const float* __restrict__ eb,
        float* __restrict__ out){
  __shared__ __align__(16) unsigned short Al[32][72];    // 4.6 KB, +8 pad
  __shared__ __align__(16) unsigned short Bl[256][72];   // 36.9 KB
  int t = threadIdx.x;
  int lane = t & 63, wid = t >> 6;      // 4 waves; wave tile 32x64
  int l15 = lane & 15, hi = lane >> 4;
  int r0 = blockIdx.x * 32;

  f32x4 acc[2][4];
  #pragma unroll
  for (int a = 0; a < 2; ++a)
    #pragma unroll
    for (int b = 0; b < 4; ++b)
      #pragma unroll
      for (int j = 0; j < 4; ++j) acc[a][b][j] = 0.f;

  int arow = t >> 3;          // 0..31
  int aoff = (t & 7) * 8;     // 0..56
  int bcol = t >> 3;          // 0..31
  int bko  = (t & 7) * 8;     // 0..56
  // clamp A row for the final block (rows 10016+ never stored)
  int agr = r0 + arow; if (agr > NROW - 1) agr = NROW - 1;
  const unsigned short* asrc = adjb + (size_t)agr * MP;

  for (int kt = 0; kt < NKT; ++kt){
    int k0 = kt * 64;
    // ---- stage A tile 32x64 (1 uint4/thread)
    *(uint4*)&Al[arow][aoff] = *(const uint4*)(asrc + k0 + aoff);
    // ---- stage B tile 256x64 (8 uint4/thread; L2-resident hsT)
    #pragma unroll
    for (int it = 0; it < 8; ++it){
      int cc = it * 32 + bcol;
      *(uint4*)&Bl[cc][bko] = *(const uint4*)(hsT + (size_t)cc * MP + k0 + bko);
    }
    __syncthreads();
    // ---- MFMA: 2x4 fragments of 16x16 per wave
    #pragma unroll
    for (int kk = 0; kk < 64; kk += 32){
      short8x a0 = *(const short8x*)&Al[l15     ][kk + hi * 8];
      short8x a1 = *(const short8x*)&Al[l15 + 16][kk + hi * 8];
      #pragma unroll
      for (int ni = 0; ni < 4; ++ni){
        short8x b = *(const short8x*)&Bl[wid*64 + ni*16 + l15][kk + hi * 8];
        acc[0][ni] = __builtin_amdgcn_mfma_f32_16x16x32_bf16(a0, b, acc[0][ni], 0, 0, 0);
        acc[1][ni] = __builtin_amdgcn_mfma_f32_16x16x32_bf16(a1, b, acc[1][ni], 0, 0, 0);
      }
    }
    __syncthreads();
  }
  // ---- fused epilogue: out = relu(dinv_i*acc + cb + eb), plain stores
  float dv[2][4];
  #pragma unroll
  for (int mi = 0; mi < 2; ++mi)
    #pragma unroll
    for (int j = 0; j < 4; ++j){
      int gr = r0 + mi*16 + hi*4 + j;
      dv[mi][j] = (gr < NROW) ? dinv[gr] : 0.f;
    }
  #pragma unroll
  for (int ni = 0; ni < 4; ++ni){
    int gc = wid*64 + ni*16 + l15;
    float bias = cb[gc] + eb[gc];
    #pragma unroll
    for (int mi = 0; mi < 2; ++mi){
      #pragma unroll
      for (int j = 0; j < 4; ++j){
        int gr = r0 + mi*16 + hi*4 + j;
        if (gr < NROW)
          out[(size_t)gr * NF + gc] =
              fmaxf(fmaf(dv[mi][j], acc[mi][ni][j], bias), 0.f);
      }
    }
  }
}

extern "C" void kernel_launch(void* const* d_in, const int* in_sizes, int n_in,
                              void* d_out, int out_size, void* d_ws, size_t ws_size,
                              hipStream_t stream){
  const float* feat = (const float*)d_in[0];
  const float* adj  = (const float*)d_in[1];
  const float* W    = (const float*)d_in[2];
  const float* cb   = (const float*)d_in[3];
  const float* eb   = (const float*)d_in[4];
  float* out = (float*)d_out;

  // ws layout: degp f32[10048] @0 ; dinv f32[10048] @256KB ;
  //            hsT bf16[256][10048] @512KB (5.15MB) ;
  //            adjb bf16[10048][10048] @8MB (202MB).
  float* degp = (float*)d_ws;
  float* dinv = (float*)((char*)d_ws + (256u << 10));
  unsigned short* hsT  = (unsigned short*)((char*)d_ws + (512u << 10));
  unsigned short* adjb = (unsigned short*)((char*)d_ws + (8u << 20));

  k_prep3<<<NROW/4,          256, 0, stream>>>(adj, adjb, degp);
  k_dinv <<<(MP + 255)/256,  256, 0, stream>>>(degp, dinv, hsT);
  k_featw<<<NROW/8,          128, 0, stream>>>(feat, W, dinv, hsT);
  k_gemm <<<NT32,            256, 0, stream>>>(adjb, hsT, dinv, cb, eb, out);
}

// Round 18
// 279.510 us; speedup vs baseline: 1.2107x; 1.2107x over previous
//
#include <hip/hip_runtime.h>
#include <hip/hip_bf16.h>

#define NROW 10000
#define NF 256
#define KF 512
#define MP 10048   // padded row/K extent (157*64)
#define NKT 157    // K-tiles of 64
#define NTILES 157 // M-tiles of 64

typedef __attribute__((ext_vector_type(8))) short short8x;
typedef __attribute__((ext_vector_type(4))) float f32x4;

// native RNE convert + pack
__device__ __forceinline__ unsigned int pkbf16(float a, float b){
  union { __hip_bfloat16 h[2]; unsigned int u; } cv;
  cv.h[0] = __float2bfloat16(a);
  cv.h[1] = __float2bfloat16(b);
  return cv.u;
}

// ---------------- k_prep3 (UNCHANGED, ~172us): fused degree + bf16 convert.
__global__ __launch_bounds__(256) void k_prep3(const float* __restrict__ adj,
        unsigned short* __restrict__ adjb, float* __restrict__ degp){
  int t = threadIdx.x, lane = t & 63;
  int row = blockIdx.x * 4 + (t >> 6);          // 2500*4 = 10000 exact
  const f32x4* src = (const f32x4*)(adj + (size_t)row * NROW);  // 2500 slots
  unsigned short* dst = adjb + (size_t)row * MP;                // 2512 slots
  const f32x4 zero4 = {0.f, 0.f, 0.f, 0.f};
  f32x4 sacc = zero4;

  for (int it = 0; it < 5; ++it){
    int base = it * 512 + lane * 2;
    f32x4 v[8];
    #pragma unroll
    for (int s = 0; s < 4; ++s){
      int fi = base + s * 128;
      v[2*s]   = (fi     < 2500) ? __builtin_nontemporal_load(src + fi)     : zero4;
      v[2*s+1] = (fi + 1 < 2500) ? __builtin_nontemporal_load(src + fi + 1) : zero4;
    }
    #pragma unroll
    for (int s = 0; s < 4; ++s){
      int fi = base + s * 128;
      int gc0 = fi * 4, gc1 = gc0 + 4;
      f32x4 w0 = v[2*s], w1 = v[2*s+1];
      if (row == gc0    ) w0[0] = 1.f;
      if (row == gc0 + 1) w0[1] = 1.f;
      if (row == gc0 + 2) w0[2] = 1.f;
      if (row == gc0 + 3) w0[3] = 1.f;
      if (row == gc1    ) w1[0] = 1.f;
      if (row == gc1 + 1) w1[1] = 1.f;
      if (row == gc1 + 2) w1[2] = 1.f;
      if (row == gc1 + 3) w1[3] = 1.f;
      sacc += w0; sacc += w1;
      uint4 o;
      o.x = pkbf16(w0[0], w0[1]);
      o.y = pkbf16(w0[2], w0[3]);
      o.z = pkbf16(w1[0], w1[1]);
      o.w = pkbf16(w1[2], w1[3]);
      if (fi < 2512) *(uint4*)(dst + gc0) = o;  // covers K-pad zeros too
    }
  }
  float s = (sacc[0] + sacc[1]) + (sacc[2] + sacc[3]);
  #pragma unroll
  for (int off = 32; off; off >>= 1) s += __shfl_down(s, off);
  if (lane == 0) degp[row] = s;
}

// ---------------- k_dinv: dinv[i] = rsqrt(deg); zero hsT K-tail rows
__global__ void k_dinv(const float* __restrict__ degp, float* __restrict__ dinv,
                       unsigned short* __restrict__ hsT){
  int i = blockIdx.x * 256 + threadIdx.x;
  if (i >= MP) return;
  float d = 0.f;
  if (i < NROW){
    float tot = degp[i];
    d = tot > 0.f ? rsqrtf(tot) : 0.f;
  }
  dinv[i] = d;
  if (i < NF){
    unsigned int* tz = (unsigned int*)(hsT + (size_t)i * MP + NROW);
    #pragma unroll
    for (int m = 0; m < (MP - NROW) / 2; ++m) tz[m] = 0u;
  }
}

// ---------------- k_featw (UNCHANGED): hsT[c][i] = bf16(dinv[i]*(feat@W)[i][c])
__global__ __launch_bounds__(128) void k_featw(const float* __restrict__ feat,
        const float* __restrict__ W, const float* __restrict__ dinv,
        unsigned short* __restrict__ hsT){
  __shared__ __align__(16) float fs[8][512];   // 16 KB
  int t = threadIdx.x;
  int i0 = blockIdx.x * 8;
  #pragma unroll
  for (int it = 0; it < 8; ++it){
    int idx = it * 128 + t;
    int r = idx >> 7, c4 = (idx & 127) * 4;
    *(float4*)&fs[r][c4] = *(const float4*)(feat + (size_t)(i0 + r) * KF + c4);
  }
  __syncthreads();
  float acc[8][2];
  #pragma unroll
  for (int r = 0; r < 8; ++r){ acc[r][0] = 0.f; acc[r][1] = 0.f; }
  int c0 = t, c1 = t + 128;
  for (int k = 0; k < KF; k += 4){
    const float* Wk = W + (size_t)k * NF;
    float w0a = Wk[c0],        w0b = Wk[c1];
    float w1a = Wk[NF + c0],   w1b = Wk[NF + c1];
    float w2a = Wk[2*NF + c0], w2b = Wk[2*NF + c1];
    float w3a = Wk[3*NF + c0], w3b = Wk[3*NF + c1];
    #pragma unroll
    for (int r = 0; r < 8; ++r){
      float4 f = *(const float4*)&fs[r][k];
      float a0 = acc[r][0], a1 = acc[r][1];
      a0 = fmaf(f.x, w0a, a0); a1 = fmaf(f.x, w0b, a1);
      a0 = fmaf(f.y, w1a, a0); a1 = fmaf(f.y, w1b, a1);
      a0 = fmaf(f.z, w2a, a0); a1 = fmaf(f.z, w2b, a1);
      a0 = fmaf(f.w, w3a, a0); a1 = fmaf(f.w, w3b, a1);
      acc[r][0] = a0; acc[r][1] = a1;
    }
  }
  float dv[8];
  #pragma unroll
  for (int r = 0; r < 8; ++r) dv[r] = dinv[i0 + r];
  unsigned short* d0 = hsT + (size_t)c0 * MP + i0;
  unsigned short* d1 = hsT + (size_t)c1 * MP + i0;
  #pragma unroll
  for (int r = 0; r < 8; r += 2){
    unsigned int u0 = pkbf16(acc[r][0] * dv[r], acc[r+1][0] * dv[r+1]);
    unsigned int u1 = pkbf16(acc[r][1] * dv[r], acc[r+1][1] * dv[r+1]);
    *(unsigned int*)(d0 + r) = u0;
    *(unsigned int*)(d1 + r) = u1;
  }
}

// ---------------- k_gemm: R8/R16 structure VERBATIM except the epilogue:
// plain stores to per-K-chunk partial buffers (chunk 0 -> d_out directly).
// Removes ~300MB of atomic HBM write-through (R9 counter evidence).
__global__ __launch_bounds__(256, 3) void k_gemm(const unsigned short* __restrict__ adjb,
        const unsigned short* __restrict__ hsT, float* __restrict__ out,
        float* __restrict__ part){
  __shared__ __align__(16) unsigned short Al[64][72];    // +8 pad: 144B stride
  __shared__ __align__(16) unsigned short Bl[256][72];
  int t = threadIdx.x;
  int lane = t & 63, wid = t >> 6;
  int wr = wid >> 1, wc = wid & 1;      // 2x2 waves, wave tile 32x128
  int r0 = blockIdx.x * 64;
  int by = blockIdx.y;                  // K chunks of {40,39,39,39} tiles
  int kt0 = by * 39 + (by > 0 ? 1 : 0);
  int kt1 = (by + 1) * 39 + 1;

  f32x4 acc[2][8];
  #pragma unroll
  for (int a = 0; a < 2; ++a)
    #pragma unroll
    for (int b = 0; b < 8; ++b)
      #pragma unroll
      for (int j = 0; j < 4; ++j) acc[a][b][j] = 0.f;

  int bcol = t >> 3;          // 0..31
  int bko  = (t & 7) * 8;     // 0..56

  for (int kt = kt0; kt < kt1; ++kt){
    int k0 = kt * 64;
    #pragma unroll
    for (int it = 0; it < 2; ++it){
      int slot = it * 256 + t;
      int row = slot >> 3, off8 = (slot & 7) * 8;
      *(uint4*)&Al[row][off8] =
          *(const uint4*)(adjb + (size_t)(r0 + row) * MP + k0 + off8);
    }
    #pragma unroll
    for (int it = 0; it < 8; ++it){
      int cc = it * 32 + bcol;
      *(uint4*)&Bl[cc][bko] = *(const uint4*)(hsT + (size_t)cc * MP + k0 + bko);
    }
    __syncthreads();
    #pragma unroll
    for (int kk = 0; kk < 64; kk += 32){
      short8x a0 = *(const short8x*)&Al[wr*32      + (lane & 15)][kk + (lane >> 4) * 8];
      short8x a1 = *(const short8x*)&Al[wr*32 + 16 + (lane & 15)][kk + (lane >> 4) * 8];
      #pragma unroll
      for (int ni = 0; ni < 8; ++ni){
        short8x b = *(const short8x*)&Bl[wc*128 + ni*16 + (lane & 15)][kk + (lane >> 4) * 8];
        acc[0][ni] = __builtin_amdgcn_mfma_f32_16x16x32_bf16(a0, b, acc[0][ni], 0, 0, 0);
        acc[1][ni] = __builtin_amdgcn_mfma_f32_16x16x32_bf16(a1, b, acc[1][ni], 0, 0, 0);
      }
    }
    __syncthreads();
  }
  // ---- epilogue: plain stores (no atomics). by==0 -> out, else part[by-1].
  float* pb = (by == 0) ? out : part + (size_t)(by - 1) * ((size_t)NROW * NF);
  #pragma unroll
  for (int mi = 0; mi < 2; ++mi){
    #pragma unroll
    for (int ni = 0; ni < 8; ++ni){
      int gc = wc*128 + ni*16 + (lane & 15);
      #pragma unroll
      for (int j = 0; j < 4; ++j){
        int gr = r0 + wr*32 + mi*16 + (lane >> 4) * 4 + j;
        if (gr < NROW) pb[(size_t)gr * NF + gc] = acc[mi][ni][j];
      }
    }
  }
}

// ---------------- k_epi: out = relu(dinv_i*(out + p0 + p1 + p2) + cb + eb)
__global__ void k_epi(float* __restrict__ out, const float* __restrict__ part,
                      const float* __restrict__ dinv, const float* __restrict__ cb,
                      const float* __restrict__ eb){
  int e = (blockIdx.x * 256 + threadIdx.x) * 4;
  int i = e >> 8, c = e & 255;
  const size_t PS = (size_t)NROW * NF;
  float4 s0 = *(const float4*)(out + e);
  float4 s1 = *(const float4*)(part + e);
  float4 s2 = *(const float4*)(part + PS + e);
  float4 s3 = *(const float4*)(part + 2*PS + e);
  float di = dinv[i];
  float4 r;
  r.x = fmaxf(fmaf((s0.x + s1.x) + (s2.x + s3.x), di, cb[c+0] + eb[c+0]), 0.f);
  r.y = fmaxf(fmaf((s0.y + s1.y) + (s2.y + s3.y), di, cb[c+1] + eb[c+1]), 0.f);
  r.z = fmaxf(fmaf((s0.z + s1.z) + (s2.z + s3.z), di, cb[c+2] + eb[c+2]), 0.f);
  r.w = fmaxf(fmaf((s0.w + s1.w) + (s2.w + s3.w), di, cb[c+3] + eb[c+3]), 0.f);
  *(float4*)(out + e) = r;
}

extern "C" void kernel_launch(void* const* d_in, const int* in_sizes, int n_in,
                              void* d_out, int out_size, void* d_ws, size_t ws_size,
                              hipStream_t stream){
  const float* feat = (const float*)d_in[0];
  const float* adj  = (const float*)d_in[1];
  const float* W    = (const float*)d_in[2];
  const float* cb   = (const float*)d_in[3];
  const float* eb   = (const float*)d_in[4];
  float* out = (float*)d_out;

  // ws layout: degp f32[10048] @0 ; dinv f32[10048] @256KB ;
  //            hsT bf16[256][10048] @512KB (5.15MB) ;
  //            part f32[3][10000][256] @6MB (30.7MB) ;
  //            adjb bf16[10048][10048] @40MB (202MB). Total ~242MB.
  float* degp = (float*)d_ws;
  float* dinv = (float*)((char*)d_ws + (256u << 10));
  unsigned short* hsT  = (unsigned short*)((char*)d_ws + (512u << 10));
  float* part = (float*)((char*)d_ws + (6u << 20));
  unsigned short* adjb = (unsigned short*)((char*)d_ws + (40u << 20));

  k_prep3<<<NROW/4,           256, 0, stream>>>(adj, adjb, degp);
  k_dinv <<<(MP + 255)/256,   256, 0, stream>>>(degp, dinv, hsT);
  k_featw<<<NROW/8,           128, 0, stream>>>(feat, W, dinv, hsT);
  k_gemm <<<dim3(NTILES, 4),  256, 0, stream>>>(adjb, hsT, out, part);
  k_epi  <<<(NROW*NF)/1024,   256, 0, stream>>>(out, part, dinv, cb, eb);
}